// Round 7
// baseline (4918.109 us; speedup 1.0000x reference)
//
#include <hip/hip_runtime.h>
#include <hip/hip_fp16.h>

typedef _Float16 f16x8 __attribute__((ext_vector_type(8)));
typedef float f32x4 __attribute__((ext_vector_type(4)));
typedef unsigned int u32x4 __attribute__((ext_vector_type(4)));
typedef unsigned int u32x2 __attribute__((ext_vector_type(2)));

static constexpr int T_SEQ = 512;
static constexpr int BATCH = 64;
static constexpr int HID   = 512;
static constexpr int VOC   = 128;

// ---- fp16 arena element offsets ----
static constexpr int AOFF_EMB  = 0;        // 128*256
static constexpr int AOFF_WXH0 = 32768;    // 512*256
static constexpr int AOFF_WHH0 = 163840;   // 512*512
static constexpr int AOFF_WXH1 = 425984;   // 512*512
static constexpr int AOFF_WHH1 = 688128;   // 512*512
static constexpr int AOFF_WHY  = 950272;   // 128*512
static constexpr int ATOT      = 1015808;

// ---- ws byte offsets ----
static constexpr size_t OFF_ARENA = 4096;
static constexpr size_t PLANE_B   = (size_t)T_SEQ * BATCH * HID * 2;  // 32 MB
static constexpr size_t OFF_XW0   = 4u << 20;           // xwf layer0 [t][n][b]
static constexpr size_t OFF_XW1   = OFF_XW0 + PLANE_B;  // xwf layer1
static constexpr size_t OFF_H0P   = OFF_XW1 + PLANE_B;  // h0 [t*64+b][n]
static constexpr size_t OFF_H1P   = OFF_H0P + PLANE_B;  // ends ~132 MB

__device__ __forceinline__ unsigned short h2u(_Float16 h) {
  union { _Float16 h; unsigned short u; } c; c.h = h; return c.u;
}
__device__ __forceinline__ _Float16 u2h(unsigned short u) {
  union { unsigned short u; _Float16 h; } c; c.u = u; return c.h;
}
// fast tanh: 1 - 2/(e^{2x}+1) via v_exp_f32 + v_rcp_f32 (~1e-7 rel; range-safe)
__device__ __forceinline__ float fast_tanh(float x) {
  float e = __expf(2.0f * x);
  return 1.0f - 2.0f * __builtin_amdgcn_rcpf(e + 1.0f);
}

// fp32 params -> fp16 arena.
__global__ __launch_bounds__(256) void canon_kernel(
    const float* p0, const float* p1, const float* p2, const float* p3,
    const float* p4, const float* p5, _Float16* __restrict__ dst) {
  const float* srcs[6] = {p0, p1, p2, p3, p4, p5};
  const int ns[6] = {32768, 131072, 262144, 262144, 262144, 65536};
  for (int i = blockIdx.x * 256 + threadIdx.x; i < ATOT; i += gridDim.x * 256) {
    int off = i, s = 0;
    while (off >= ns[s]) { off -= ns[s]; ++s; }
    dst[i] = (_Float16)srcs[s][off];
  }
}

// xwf0[t][n][b] = emb[x[b,t]][:] . Wxh0[n][:] + bh0[n].  Grid (512, 8) x 256.
__global__ __launch_bounds__(256) void xw0_kernel(
    const int* __restrict__ x, const _Float16* __restrict__ emb,
    const _Float16* __restrict__ Wxh, const float* __restrict__ bh,
    _Float16* __restrict__ xwf) {
  __shared__ _Float16 Bs[64][264];
  const int t = blockIdx.x, n0 = blockIdx.y * 64, tid = threadIdx.x;
#pragma unroll
  for (int rep = 0; rep < 8; ++rep) {
    int flat = rep * 256 + tid;
    int row = flat >> 5, c8 = flat & 31;
    *(f16x8*)&Bs[row][c8 * 8] = *(const f16x8*)&Wxh[(size_t)(n0 + row) * 256 + c8 * 8];
  }
  __syncthreads();
  const int wv = tid >> 6, lane = tid & 63, l15 = lane & 15, quad = lane >> 4;
  const int b = wv * 16 + l15;
  const int idx = x[b * 512 + t];
  f32x4 acc[4];
#pragma unroll
  for (int nt = 0; nt < 4; ++nt) { float bv = bh[n0 + nt * 16 + l15]; acc[nt] = {bv, bv, bv, bv}; }
#pragma unroll
  for (int kc = 0; kc < 8; ++kc) {
    f16x8 a = *(const f16x8*)&emb[(size_t)idx * 256 + kc * 32 + quad * 8];
#pragma unroll
    for (int nt = 0; nt < 4; ++nt) {
      f16x8 bf = *(const f16x8*)&Bs[nt * 16 + l15][kc * 32 + quad * 8];
      acc[nt] = __builtin_amdgcn_mfma_f32_16x16x32_f16(a, bf, acc[nt], 0, 0, 0);
    }
  }
  // C-layout: n = n0+nt*16+l15 (col), b-row = wv*16+quad*4+r. Pack 4 r as b64.
#pragma unroll
  for (int nt = 0; nt < 4; ++nt) {
    unsigned int lo = (unsigned int)h2u((_Float16)acc[nt][0]) |
                      ((unsigned int)h2u((_Float16)acc[nt][1]) << 16);
    unsigned int hi = (unsigned int)h2u((_Float16)acc[nt][2]) |
                      ((unsigned int)h2u((_Float16)acc[nt][3]) << 16);
    u32x2 pk = {lo, hi};
    *(u32x2*)&xwf[(size_t)t * 32768 + (size_t)(n0 + nt * 16 + l15) * 64 + wv * 16 + quad * 4] = pk;
  }
}

// xwf1[t][n][b] = h0[t*64+b][:] . Wxh1[n][:] + bh1[n].  Grid (512, 16) x 256.
__global__ __launch_bounds__(256) void xw1_kernel(
    const _Float16* __restrict__ hin, const _Float16* __restrict__ Wxh,
    const float* __restrict__ bh, _Float16* __restrict__ xwf) {
  __shared__ _Float16 Bs[32][520];
  const int t = blockIdx.x, n0 = blockIdx.y * 32, tid = threadIdx.x;
#pragma unroll
  for (int rep = 0; rep < 8; ++rep) {
    int flat = rep * 256 + tid;
    int row = flat >> 6, c8 = flat & 63;
    *(f16x8*)&Bs[row][c8 * 8] = *(const f16x8*)&Wxh[(size_t)(n0 + row) * 512 + c8 * 8];
  }
  __syncthreads();
  const int wv = tid >> 6, lane = tid & 63, l15 = lane & 15, quad = lane >> 4;
  const int m = t * 64 + wv * 16 + l15;
  f32x4 acc[2];
#pragma unroll
  for (int nt = 0; nt < 2; ++nt) { float bv = bh[n0 + nt * 16 + l15]; acc[nt] = {bv, bv, bv, bv}; }
#pragma unroll
  for (int kc = 0; kc < 16; ++kc) {
    f16x8 a = *(const f16x8*)&hin[(size_t)m * 512 + kc * 32 + quad * 8];
#pragma unroll
    for (int nt = 0; nt < 2; ++nt) {
      f16x8 bf = *(const f16x8*)&Bs[nt * 16 + l15][kc * 32 + quad * 8];
      acc[nt] = __builtin_amdgcn_mfma_f32_16x16x32_f16(a, bf, acc[nt], 0, 0, 0);
    }
  }
#pragma unroll
  for (int nt = 0; nt < 2; ++nt) {
    unsigned int lo = (unsigned int)h2u((_Float16)acc[nt][0]) |
                      ((unsigned int)h2u((_Float16)acc[nt][1]) << 16);
    unsigned int hi = (unsigned int)h2u((_Float16)acc[nt][2]) |
                      ((unsigned int)h2u((_Float16)acc[nt][3]) << 16);
    u32x2 pk = {lo, hi};
    *(u32x2*)&xwf[(size_t)t * 32768 + (size_t)(n0 + nt * 16 + l15) * 64 + wv * 16 + quad * 4] = pk;
  }
}

// Sync-free recurrence: grid = 4 blocks x 512 thr. Block g owns batches
// [16g,16g+16) end-to-end; full 512x512 W_hh register-resident across 8 waves
// (wave -> 64 output cols = 256 regs of weights/wave) using the gfx950
// UNIFIED VGPR/AGPR file: tiles 0-1 pinned to VGPRs ("+v"), tiles 2-3 pinned
// to AGPRs ("+a") — MFMA reads B-operands from either class (isa §10).
// h_t in LDS double buffer; no atomics, no fences, one barrier per step.
__global__ __launch_bounds__(512, 1) void rnn_seq_kernel(
    const _Float16* __restrict__ Whh,   // (512 n, 512 k)
    const _Float16* __restrict__ xwf,   // [t][n][b] fragment layout
    _Float16* __restrict__ hplain)      // [t*64+b][n]
{
  const int g = blockIdx.x;
  const int tid = threadIdx.x, wv = tid >> 6, lane = tid & 63;
  const int l15 = lane & 15, quad = lane >> 4;
  const int bb = g * 16;
  const int n0 = wv * 64;

  __shared__ _Float16 hbuf[2][16][520];

  // B[k=quad*8+j][n=l15] = Whh[n0+tile*16+l15][kc*32+quad*8+j]
  u32x4 Bv[2][16];   // tiles 0,1 -> VGPR-pinned
  u32x4 Ba[2][16];   // tiles 2,3 -> AGPR-pinned
#pragma unroll
  for (int tile = 0; tile < 2; ++tile)
#pragma unroll
    for (int kc = 0; kc < 16; ++kc)
      Bv[tile][kc] = *(const u32x4*)&Whh[(size_t)(n0 + tile * 16 + l15) * 512 + kc * 32 + quad * 8];
#pragma unroll
  for (int tile = 0; tile < 2; ++tile)
#pragma unroll
    for (int kc = 0; kc < 16; ++kc)
      Ba[tile][kc] = *(const u32x4*)&Whh[(size_t)(n0 + (tile + 2) * 16 + l15) * 512 + kc * 32 + quad * 8];
  // Pin: values become asm-opaque so the per-step barrier can't force re-loads.
#pragma unroll
  for (int tile = 0; tile < 2; ++tile)
#pragma unroll
    for (int kc = 0; kc < 16; ++kc) {
      asm volatile("" : "+v"(Bv[tile][kc]));
      asm volatile("" : "+a"(Ba[tile][kc]));
    }

  // xw prefetch for t=0 (4 x 8B loads/lane)
  const _Float16* xwb = xwf + (size_t)(n0 + l15) * 64 + bb + quad * 4;
  u32x2 pf[4];
#pragma unroll
  for (int tile = 0; tile < 4; ++tile)
    pf[tile] = *(const u32x2*)(xwb + (size_t)tile * 16 * 64);

  for (int t = 0; t < T_SEQ; ++t) {
    f32x4 acc[4];
#pragma unroll
    for (int tile = 0; tile < 4; ++tile) {
      u32x2 p = pf[tile];
      acc[tile][0] = (float)u2h((unsigned short)(p.x & 0xFFFFu));
      acc[tile][1] = (float)u2h((unsigned short)(p.x >> 16));
      acc[tile][2] = (float)u2h((unsigned short)(p.y & 0xFFFFu));
      acc[tile][3] = (float)u2h((unsigned short)(p.y >> 16));
    }
    if (t + 1 < T_SEQ) {
      const _Float16* nx = xwb + (size_t)(t + 1) * 32768;
#pragma unroll
      for (int tile = 0; tile < 4; ++tile)
        pf[tile] = *(const u32x2*)(nx + (size_t)tile * 16 * 64);
    }

    if (t > 0) {
      const int p = (t - 1) & 1;
#pragma unroll
      for (int kc = 0; kc < 16; ++kc) {
        f16x8 a = *(const f16x8*)&hbuf[p][l15][kc * 32 + quad * 8];
        acc[0] = __builtin_amdgcn_mfma_f32_16x16x32_f16(
            a, __builtin_bit_cast(f16x8, Bv[0][kc]), acc[0], 0, 0, 0);
        acc[1] = __builtin_amdgcn_mfma_f32_16x16x32_f16(
            a, __builtin_bit_cast(f16x8, Bv[1][kc]), acc[1], 0, 0, 0);
        acc[2] = __builtin_amdgcn_mfma_f32_16x16x32_f16(
            a, __builtin_bit_cast(f16x8, Ba[0][kc]), acc[2], 0, 0, 0);
        acc[3] = __builtin_amdgcn_mfma_f32_16x16x32_f16(
            a, __builtin_bit_cast(f16x8, Ba[1][kc]), acc[3], 0, 0, 0);
      }
    }

    // epilogue: tanh, write LDS (next buf) + global (fire-and-forget)
    const int pn = t & 1;
    _Float16* hrow = hplain + (size_t)(t * 64 + bb + quad * 4) * 512 + n0 + l15;
#pragma unroll
    for (int tile = 0; tile < 4; ++tile)
#pragma unroll
      for (int r = 0; r < 4; ++r) {
        _Float16 hh = (_Float16)fast_tanh(acc[tile][r]);
        hbuf[pn][quad * 4 + r][n0 + tile * 16 + l15] = hh;
        hrow[(size_t)r * 512 + tile * 16] = hh;
      }
    __syncthreads();
  }
}

// logits[b][t][v] = h1[t*64+b][:] . Why[v][:] + by[v].  Grid 512 x 256.
__global__ __launch_bounds__(256) void logits_kernel(
    const _Float16* __restrict__ h1, const _Float16* __restrict__ Why,
    const float* __restrict__ by, float* __restrict__ out) {
  const int t = blockIdx.x;
  const int wv = threadIdx.x >> 6, lane = threadIdx.x & 63;
  const int l15 = lane & 15, quad = lane >> 4, bb = wv * 16;
  f32x4 acc[8];
#pragma unroll
  for (int vt = 0; vt < 8; ++vt) { float bv = by[vt * 16 + l15]; acc[vt] = {bv, bv, bv, bv}; }
#pragma unroll
  for (int kc = 0; kc < 16; ++kc) {
    f16x8 a = *(const f16x8*)&h1[(size_t)(t * 64 + bb + l15) * 512 + kc * 32 + quad * 8];
#pragma unroll
    for (int vt = 0; vt < 8; ++vt) {
      f16x8 b = *(const f16x8*)&Why[(size_t)(vt * 16 + l15) * 512 + kc * 32 + quad * 8];
      acc[vt] = __builtin_amdgcn_mfma_f32_16x16x32_f16(a, b, acc[vt], 0, 0, 0);
    }
  }
#pragma unroll
  for (int vt = 0; vt < 8; ++vt)
#pragma unroll
    for (int r = 0; r < 4; ++r)
      out[((size_t)(bb + quad * 4 + r) * 512 + t) * 128 + vt * 16 + l15] = acc[vt][r];
}

__global__ void hlast_kernel(const _Float16* __restrict__ h0,
                             const _Float16* __restrict__ h1,
                             float* __restrict__ out) {
  const size_t LOG = (size_t)BATCH * T_SEQ * VOC;
  const size_t HL = (size_t)BATCH * HID;
  const size_t base = (size_t)(T_SEQ - 1) * BATCH * HID;
  int tid = blockIdx.x * 256 + threadIdx.x;
  if (tid < (int)HL) {
    out[LOG + tid]      = (float)h0[base + tid];
    out[LOG + HL + tid] = (float)h1[base + tid];
  }
}

extern "C" void kernel_launch(void* const* d_in, const int* in_sizes, int n_in,
                              void* d_out, int out_size, void* d_ws, size_t ws_size,
                              hipStream_t stream) {
  const int* x = (const int*)d_in[0];
  float* out = (float*)d_out;
  char* ws = (char*)d_ws;
  _Float16* arena = (_Float16*)(ws + OFF_ARENA);
  _Float16* xw0f = (_Float16*)(ws + OFF_XW0);
  _Float16* xw1f = (_Float16*)(ws + OFF_XW1);
  _Float16* h0p  = (_Float16*)(ws + OFF_H0P);
  _Float16* h1p  = (_Float16*)(ws + OFF_H1P);

  canon_kernel<<<512, 256, 0, stream>>>(
      (const float*)d_in[1], (const float*)d_in[2], (const float*)d_in[3],
      (const float*)d_in[5], (const float*)d_in[6], (const float*)d_in[8], arena);

  xw0_kernel<<<dim3(512, 8), 256, 0, stream>>>(
      x, arena + AOFF_EMB, arena + AOFF_WXH0, (const float*)d_in[4], xw0f);

  rnn_seq_kernel<<<4, 512, 0, stream>>>(arena + AOFF_WHH0, xw0f, h0p);

  xw1_kernel<<<dim3(512, 16), 256, 0, stream>>>(
      h0p, arena + AOFF_WXH1, (const float*)d_in[7], xw1f);

  rnn_seq_kernel<<<4, 512, 0, stream>>>(arena + AOFF_WHH1, xw1f, h1p);

  logits_kernel<<<512, 256, 0, stream>>>(
      h1p, arena + AOFF_WHY, (const float*)d_in[9], out);

  hlast_kernel<<<(BATCH * HID + 255) / 256, 256, 0, stream>>>(h0p, h1p, out);
}